// Round 4
// baseline (316.603 us; speedup 1.0000x reference)
//
#include <hip/hip_runtime.h>

#define L_DIM 2048
#define B_DIM 8
#define DD    1024
#define M_DIM 16384     // L*B
#define N_DIM 3072      // 3*D
#define K_DIM 1024
#define CH    8192      // B*D channels
#define CH8   1024      // CH/8 (vec8 units per l-step)
#define NSEG  128
#define LSEG  16
#define LN_EPS 1e-5f

typedef __attribute__((ext_vector_type(8))) short bf16x8;
typedef __attribute__((ext_vector_type(8))) unsigned short u16x8;
typedef __attribute__((ext_vector_type(4))) float f32x4;

__device__ __forceinline__ unsigned short f2bf(float f){
  unsigned u = __float_as_uint(f);
  u += 0x7fffu + ((u >> 16) & 1u);
  return (unsigned short)(u >> 16);
}
__device__ __forceinline__ float bf2f(unsigned short h){
  return __uint_as_float(((unsigned)h) << 16);
}
__device__ __forceinline__ float fsigmoid(float z){ return 1.0f/(1.0f + __expf(-z)); }
__device__ __forceinline__ float ftanh(float z){ return 1.0f - 2.0f/(1.0f + __expf(2.0f*z)); }

// ------- LayerNorm: wave-per-row, 4 rows/block, no barriers -------
__global__ __launch_bounds__(256) void ln_kernel(const float* __restrict__ x,
                                                 const float* __restrict__ g,
                                                 const float* __restrict__ bta,
                                                 unsigned short* __restrict__ xn)
{
  int tid  = threadIdx.x;
  int wave = tid >> 6, lane = tid & 63;
  int row  = blockIdx.x * 4 + wave;
  const float4* xr = (const float4*)(x + (size_t)row * DD);
  float4 v[4];
  #pragma unroll
  for (int k = 0; k < 4; k++) v[k] = xr[lane + k * 64];
  float s = 0.f, sq = 0.f;
  #pragma unroll
  for (int k = 0; k < 4; k++) {
    s  += v[k].x + v[k].y + v[k].z + v[k].w;
    sq += v[k].x*v[k].x + v[k].y*v[k].y + v[k].z*v[k].z + v[k].w*v[k].w;
  }
  #pragma unroll
  for (int off = 32; off > 0; off >>= 1) {
    s  += __shfl_down(s,  off, 64);
    sq += __shfl_down(sq, off, 64);
  }
  s  = __shfl(s,  0, 64);
  sq = __shfl(sq, 0, 64);
  float mean = s * (1.0f / DD);
  float var  = sq * (1.0f / DD) - mean * mean;
  float rstd = rsqrtf(var + LN_EPS);
  ushort4* xo = (ushort4*)(xn + (size_t)row * DD);
  #pragma unroll
  for (int k = 0; k < 4; k++) {
    float4 gg = ((const float4*)g)[lane + k * 64];
    float4 bb = ((const float4*)bta)[lane + k * 64];
    ushort4 o;
    o.x = f2bf((v[k].x - mean) * rstd * gg.x + bb.x);
    o.y = f2bf((v[k].y - mean) * rstd * gg.y + bb.y);
    o.z = f2bf((v[k].z - mean) * rstd * gg.z + bb.z);
    o.w = f2bf((v[k].w - mean) * rstd * gg.w + bb.w);
    xo[lane + k * 64] = o;
  }
}

// ---------------- W fp32 [3072,1024] -> bf16 same layout ----------------
__global__ __launch_bounds__(256) void wconv_kernel(const float* __restrict__ W,
                                                    unsigned short* __restrict__ wb)
{
  int gid = blockIdx.x * 256 + threadIdx.x;
  float4 v = ((const float4*)W)[gid];
  ushort4 o;
  o.x = f2bf(v.x); o.y = f2bf(v.y); o.z = f2bf(v.z); o.w = f2bf(v.w);
  ((ushort4*)wb)[gid] = o;
}

// ---------------- GEMM: ufr = xn * W^T + b, fused activations ----------------
// R0 structure (128x128, BK=64, XOR-swizzled staging, single buffer) with LDS
// capped at EXACTLY 32 KiB (epilogue transposed in two 64-row halves) so
// 5 blocks/CU fit (160/32). Occupancy experiment: all schedules so far ran at
// ~2 waves/SIMD; m114-style inter-block overlap needs 4-5 blocks/CU.
#define BM 128
#define BN 128
#define BK 64
#define LDP 136        // epilogue leading dim (shorts); half-epilogue = 64*136*2 = 17.4KB

#define GLDS16(gp, lp) __builtin_amdgcn_global_load_lds( \
    (const __attribute__((address_space(1))) void*)(gp), \
    (__attribute__((address_space(3))) void*)(lp), 16, 0, 0)

__global__ __launch_bounds__(256, 5) void gemm_gates(const unsigned short* __restrict__ A,
                                                     const unsigned short* __restrict__ Bw,
                                                     const float* __restrict__ bias,
                                                     unsigned short* __restrict__ u_t,
                                                     unsigned short* __restrict__ f_g,
                                                     unsigned short* __restrict__ r_g)
{
  __shared__ unsigned short smem[16384];          // 32,768 B exactly
  unsigned short* sA = smem;
  unsigned short* sB = smem + BM * BK;            // 8192 shorts each
  int tid  = threadIdx.x;
  int wave = tid >> 6, lane = tid & 63;
  int bm0 = blockIdx.x * BM;
  int bn0 = blockIdx.y * BN;

  f32x4 zero = {0.f, 0.f, 0.f, 0.f};
  f32x4 acc[4][4];
  #pragma unroll
  for (int i = 0; i < 4; i++)
    #pragma unroll
    for (int j = 0; j < 4; j++) acc[i][j] = zero;

  int q8  = lane >> 3;
  int rr8 = lane & 7;
  int sch = rr8 ^ q8;        // XOR swizzle source chunk
  const unsigned short* a_lane = A  + (size_t)(bm0 + wave * 32 + q8) * K_DIM + sch * 8;
  const unsigned short* b_lane = Bw + (size_t)(bn0 + wave * 32 + q8) * K_DIM + sch * 8;

  int wm = (wave & 1) * 64, wn = (wave >> 1) * 64;
  int fm = lane & 15, quad = lane >> 4;
  int f7 = fm & 7;

  for (int k0 = 0; k0 < K_DIM; k0 += BK) {
    #pragma unroll
    for (int i = 0; i < 4; i++) {
      GLDS16(a_lane + (size_t)(i * 8) * K_DIM + k0, &sA[(wave * 32 + i * 8) * BK]);
      GLDS16(b_lane + (size_t)(i * 8) * K_DIM + k0, &sB[(wave * 32 + i * 8) * BK]);
    }
    __syncthreads();

    #pragma unroll
    for (int kk = 0; kk < 2; kk++) {
      bf16x8 af[4], bfr[4];
      #pragma unroll
      for (int i = 0; i < 4; i++) {
        int slot = (kk * 4 + quad) ^ f7;
        af[i]  = *(const bf16x8*)&sA[(wm + i * 16 + fm) * BK + slot * 8];
        bfr[i] = *(const bf16x8*)&sB[(wn + i * 16 + fm) * BK + slot * 8];
      }
      #pragma unroll
      for (int mi = 0; mi < 4; mi++)
        #pragma unroll
        for (int ni = 0; ni < 4; ni++)
          acc[mi][ni] = __builtin_amdgcn_mfma_f32_16x16x32_bf16(af[mi], bfr[ni], acc[mi][ni], 0, 0, 0);
    }
    __syncthreads();
  }

  int slice = bn0 >> 10;
  int nd0   = bn0 & 1023;
  unsigned short* dst = (slice == 0) ? u_t : ((slice == 1) ? f_g : r_g);

  // two-half epilogue: rows [h*64, h*64+64) staged in 64*LDP shorts (17.4 KB)
  #pragma unroll
  for (int h = 0; h < 2; ++h) {
    if ((wave & 1) == h) {
      #pragma unroll
      for (int ni = 0; ni < 4; ni++) {
        int lcol = wn + ni * 16 + fm;
        float bia = bias[bn0 + lcol];
        #pragma unroll
        for (int mi = 0; mi < 4; mi++) {
          #pragma unroll
          for (int reg = 0; reg < 4; reg++) {
            int lrow = mi * 16 + quad * 4 + reg;       // 0..63 within half
            float v = acc[mi][ni][reg] + bia;
            float act = (slice == 0) ? ftanh(v) : fsigmoid(v);
            smem[lrow * LDP + lcol] = f2bf(act);
          }
        }
      }
    }
    __syncthreads();
    #pragma unroll
    for (int it = 0; it < 4; ++it) {
      int row = it * 16 + (tid >> 4);
      int cc  = (tid & 15) * 8;
      u16x8 v = *(const u16x8*)&smem[row * LDP + cc];
      *(u16x8*)(dst + (size_t)(bm0 + h * 64 + row) * DD + nd0 + cc) = v;
    }
    __syncthreads();
  }
}

// ---- scan pass 1: per-segment affine summary, vec8 channels, 16B loads ----
// segment = 16 l-steps; P,E stored bf16 [NSEG][CH]
__global__ __launch_bounds__(256) void scan_pass1(const unsigned short* __restrict__ f_g,
                                                  const unsigned short* __restrict__ u_t,
                                                  unsigned short* __restrict__ P,
                                                  unsigned short* __restrict__ E)
{
  int vc8 = blockIdx.x * 256 + threadIdx.x;   // 0..1023
  int seg = blockIdx.y;                       // 0..127
  const u16x8* f8 = (const u16x8*)f_g;
  const u16x8* u8 = (const u16x8*)u_t;
  size_t g = (size_t)(seg * LSEG) * CH8 + vc8;
  float p[8], e[8];
  #pragma unroll
  for (int k = 0; k < 8; k++) { p[k] = 1.f; e[k] = 0.f; }
  #pragma unroll 4
  for (int i = 0; i < LSEG; i++) {
    u16x8 ff = f8[g];
    u16x8 uu = u8[g];
    #pragma unroll
    for (int k = 0; k < 8; k++) {
      float fv = bf2f(ff[k]);
      e[k] = fv * e[k] + (1.f - fv) * bf2f(uu[k]);
      p[k] *= fv;
    }
    g += CH8;
  }
  u16x8 pv, ev;
  #pragma unroll
  for (int k = 0; k < 8; k++) { pv[k] = f2bf(p[k]); ev[k] = f2bf(e[k]); }
  ((u16x8*)P)[(size_t)seg * CH8 + vc8] = pv;
  ((u16x8*)E)[(size_t)seg * CH8 + vc8] = ev;
}

// ---- scan pass 2: scan 128 segment summaries per channel ----
__global__ __launch_bounds__(128) void scan_pass2(const unsigned short* __restrict__ P,
                                                  const unsigned short* __restrict__ E,
                                                  const float* __restrict__ c0,
                                                  float* __restrict__ Cini,
                                                  float* __restrict__ lastc)
{
  int ch = blockIdx.x * 128 + threadIdx.x;    // 64 blocks x 128
  float c = c0[ch];
  #pragma unroll 8
  for (int s = 0; s < NSEG; s++) {
    Cini[(size_t)s * CH + ch] = c;
    c = bf2f(P[(size_t)s * CH + ch]) * c + bf2f(E[(size_t)s * CH + ch]);
  }
  lastc[ch] = c;
}

// ---- scan pass 3: replay with true init + fused output, vec8, 16B loads ----
__global__ __launch_bounds__(256) void scan_pass3(const unsigned short* __restrict__ f_g,
                                                  const unsigned short* __restrict__ u_t,
                                                  const unsigned short* __restrict__ r_g,
                                                  const float* __restrict__ x,
                                                  const unsigned short* __restrict__ xn,
                                                  const float* __restrict__ Cini,
                                                  float* __restrict__ out)
{
  int vc8 = blockIdx.x * 256 + threadIdx.x;   // 0..1023
  int seg = blockIdx.y;                       // 0..127
  const u16x8* f8 = (const u16x8*)f_g;
  const u16x8* u8 = (const u16x8*)u_t;
  const u16x8* r8 = (const u16x8*)r_g;
  const u16x8* n8 = (const u16x8*)xn;
  const float4* x4 = (const float4*)x;
  float4* o4 = (float4*)out;
  float c[8];
  {
    const float4* C4 = (const float4*)Cini;
    size_t ci = (size_t)seg * (CH / 4) + (size_t)vc8 * 2;
    float4 ca = C4[ci], cb = C4[ci + 1];
    c[0]=ca.x; c[1]=ca.y; c[2]=ca.z; c[3]=ca.w;
    c[4]=cb.x; c[5]=cb.y; c[6]=cb.z; c[7]=cb.w;
  }
  size_t g = (size_t)(seg * LSEG) * CH8 + vc8;
  #pragma unroll 2
  for (int i = 0; i < LSEG; i++) {
    u16x8 ff = f8[g];
    u16x8 uu = u8[g];
    u16x8 rr = r8[g];
    u16x8 nn = n8[g];
    size_t xi = g * 2;                 // float4 index (8 floats = 2 float4)
    float4 xa = x4[xi], xb = x4[xi + 1];
    float ov[8];
    #pragma unroll
    for (int k = 0; k < 8; k++) {
      float fv = bf2f(ff[k]);
      c[k] = fv * c[k] + (1.f - fv) * bf2f(uu[k]);
      float rv = bf2f(rr[k]);
      ov[k] = rv * ftanh(c[k]) + (1.f - rv) * bf2f(nn[k]);
    }
    o4[xi]     = (float4){xa.x + ov[0], xa.y + ov[1], xa.z + ov[2], xa.w + ov[3]};
    o4[xi + 1] = (float4){xb.x + ov[4], xb.y + ov[5], xb.z + ov[6], xb.w + ov[7]};
    g += CH8;
  }
}

extern "C" void kernel_launch(void* const* d_in, const int* in_sizes, int n_in,
                              void* d_out, int out_size, void* d_ws, size_t ws_size,
                              hipStream_t stream) {
  const float* x    = (const float*)d_in[0];
  const float* c0   = (const float*)d_in[1];
  const float* W    = (const float*)d_in[2];
  const float* bias = (const float*)d_in[3];
  const float* ln_g = (const float*)d_in[4];
  const float* ln_b = (const float*)d_in[5];
  float* out = (float*)d_out;

  char* ws = (char*)d_ws;
  unsigned short* xn  = (unsigned short*)(ws);                 // 33,554,432 B
  unsigned short* wb  = (unsigned short*)(ws + 33554432ULL);   //  6,291,456 B (dead after gemm)
  unsigned short* u_t = (unsigned short*)(ws + 39845888ULL);   // 33,554,432 B
  unsigned short* f_g = (unsigned short*)(ws + 73400320ULL);   // 33,554,432 B
  unsigned short* r_g = (unsigned short*)(ws + 106954752ULL);  // 33,554,432 B
  // P,E (bf16, 2 MB each) reuse wb's region after gemm completes:
  unsigned short* Pseg = (unsigned short*)(ws + 33554432ULL);  // 2,097,152 B
  unsigned short* Eseg = (unsigned short*)(ws + 35651584ULL);  // 2,097,152 B
  float* Cini = (float*)(ws + 140509184ULL);                   // 4,194,304 B (ends 144,703,488)

  ln_kernel   <<<M_DIM / 4, 256, 0, stream>>>(x, ln_g, ln_b, xn);
  wconv_kernel<<<N_DIM, 256, 0, stream>>>(W, wb);
  gemm_gates  <<<dim3(M_DIM / BM, N_DIM / BN), 256, 0, stream>>>(xn, wb, bias, u_t, f_g, r_g);
  scan_pass1  <<<dim3(CH8 / 256, NSEG), 256, 0, stream>>>(f_g, u_t, Pseg, Eseg);
  scan_pass2  <<<CH / 128, 128, 0, stream>>>(Pseg, Eseg, c0, Cini, out + (size_t)M_DIM * DD);
  scan_pass3  <<<dim3(CH8 / 256, NSEG), 256, 0, stream>>>(f_g, u_t, r_g, x, xn, Cini, out);
}

// Round 5
// 239.637 us; speedup vs baseline: 1.3212x; 1.3212x over previous
//
#include <hip/hip_runtime.h>

#define L_DIM 2048
#define B_DIM 8
#define DD    1024
#define M_DIM 16384     // L*B
#define N_DIM 3072      // 3*D
#define K_DIM 1024
#define CH    8192      // B*D channels
#define CH8   1024      // CH/8 (vec8 units per l-step)
#define NSEG  128
#define LSEG  16
#define LN_EPS 1e-5f

typedef __attribute__((ext_vector_type(8))) short bf16x8;
typedef __attribute__((ext_vector_type(8))) unsigned short u16x8;
typedef __attribute__((ext_vector_type(4))) float f32x4;

__device__ __forceinline__ unsigned short f2bf(float f){
  unsigned u = __float_as_uint(f);
  u += 0x7fffu + ((u >> 16) & 1u);
  return (unsigned short)(u >> 16);
}
__device__ __forceinline__ float bf2f(unsigned short h){
  return __uint_as_float(((unsigned)h) << 16);
}
__device__ __forceinline__ float fsigmoid(float z){ return 1.0f/(1.0f + __expf(-z)); }
__device__ __forceinline__ float ftanh(float z){ return 1.0f - 2.0f/(1.0f + __expf(2.0f*z)); }

// ------- LayerNorm: wave-per-row, 4 rows/block, no barriers -------
__global__ __launch_bounds__(256) void ln_kernel(const float* __restrict__ x,
                                                 const float* __restrict__ g,
                                                 const float* __restrict__ bta,
                                                 unsigned short* __restrict__ xn)
{
  int tid  = threadIdx.x;
  int wave = tid >> 6, lane = tid & 63;
  int row  = blockIdx.x * 4 + wave;
  const float4* xr = (const float4*)(x + (size_t)row * DD);
  float4 v[4];
  #pragma unroll
  for (int k = 0; k < 4; k++) v[k] = xr[lane + k * 64];
  float s = 0.f, sq = 0.f;
  #pragma unroll
  for (int k = 0; k < 4; k++) {
    s  += v[k].x + v[k].y + v[k].z + v[k].w;
    sq += v[k].x*v[k].x + v[k].y*v[k].y + v[k].z*v[k].z + v[k].w*v[k].w;
  }
  #pragma unroll
  for (int off = 32; off > 0; off >>= 1) {
    s  += __shfl_down(s,  off, 64);
    sq += __shfl_down(sq, off, 64);
  }
  s  = __shfl(s,  0, 64);
  sq = __shfl(sq, 0, 64);
  float mean = s * (1.0f / DD);
  float var  = sq * (1.0f / DD) - mean * mean;
  float rstd = rsqrtf(var + LN_EPS);
  ushort4* xo = (ushort4*)(xn + (size_t)row * DD);
  #pragma unroll
  for (int k = 0; k < 4; k++) {
    float4 gg = ((const float4*)g)[lane + k * 64];
    float4 bb = ((const float4*)bta)[lane + k * 64];
    ushort4 o;
    o.x = f2bf((v[k].x - mean) * rstd * gg.x + bb.x);
    o.y = f2bf((v[k].y - mean) * rstd * gg.y + bb.y);
    o.z = f2bf((v[k].z - mean) * rstd * gg.z + bb.z);
    o.w = f2bf((v[k].w - mean) * rstd * gg.w + bb.w);
    xo[lane + k * 64] = o;
  }
}

// ---------------- W fp32 [3072,1024] -> bf16 same layout ----------------
__global__ __launch_bounds__(256) void wconv_kernel(const float* __restrict__ W,
                                                    unsigned short* __restrict__ wb)
{
  int gid = blockIdx.x * 256 + threadIdx.x;
  float4 v = ((const float4*)W)[gid];
  ushort4 o;
  o.x = f2bf(v.x); o.y = f2bf(v.y); o.z = f2bf(v.z); o.w = f2bf(v.w);
  ((ushort4*)wb)[gid] = o;
}

// ---------------- GEMM: ufr = xn * W^T + b, fused activations ----------------
// BM=256 x BN=128, BK=64, 8 waves (2M x 4N; per-wave 128x32 -> acc[8][2] = 64
// AGPRs, keeping unified regs <= 128/wave so 4 waves/SIMD fit). Single-buffer
// LDS = 48 KB -> 2 blocks/CU (96 KB), giving inter-block overlap of the
// barrier drains (m114) while the 256-tall tile + XCD swizzle keep FETCH low.
// Simple compiler-visible loop (R2/R3 proved asm micro-scheduling is null here).
#define BM 256
#define BN 128
#define BK 64
#define LDP 136        // epilogue chunk leading dim (shorts); 64*136*2 = 17.4 KB

#define GLDS16(gp, lp) __builtin_amdgcn_global_load_lds( \
    (const __attribute__((address_space(1))) void*)(gp), \
    (__attribute__((address_space(3))) void*)(lp), 16, 0, 0)

__global__ __launch_bounds__(512, 4) void gemm_gates(const unsigned short* __restrict__ A,
                                                     const unsigned short* __restrict__ Bw,
                                                     const float* __restrict__ bias,
                                                     unsigned short* __restrict__ u_t,
                                                     unsigned short* __restrict__ f_g,
                                                     unsigned short* __restrict__ r_g)
{
  __shared__ unsigned short smem[24576];          // 49,152 B
  unsigned short* sA = smem;                      // 256*64 shorts = 32 KB
  unsigned short* sB = smem + BM * BK;            // 128*64 shorts = 16 KB
  int tid  = threadIdx.x;
  int wave = tid >> 6, lane = tid & 63;

  // ---- bijective XCD swizzle: nwg = 64*24 = 1536, 1536/8 = 192 per XCD ----
  int lin = blockIdx.y * 64 + blockIdx.x;
  int swz = (lin & 7) * 192 + (lin >> 3);
  int bx = swz & 63, by = swz >> 6;
  int bm0 = bx * BM;
  int bn0 = by * BN;

  f32x4 zero = {0.f, 0.f, 0.f, 0.f};
  f32x4 acc[8][2];
  #pragma unroll
  for (int i = 0; i < 8; i++)
    #pragma unroll
    for (int j = 0; j < 2; j++) acc[i][j] = zero;

  int q8  = lane >> 3;
  int rr8 = lane & 7;
  int sch = rr8 ^ q8;        // XOR swizzle source chunk
  const unsigned short* a_lane = A  + (size_t)(bm0 + wave * 32 + q8) * K_DIM + sch * 8;
  const unsigned short* b_lane = Bw + (size_t)(bn0 + wave * 16 + q8) * K_DIM + sch * 8;

  int wm = (wave >> 2) * 128, wn = (wave & 3) * 32;   // per-wave output origin
  int fm = lane & 15, quad = lane >> 4;
  int f7 = fm & 7;

  for (int k0 = 0; k0 < K_DIM; k0 += BK) {
    #pragma unroll
    for (int i = 0; i < 4; i++)
      GLDS16(a_lane + (size_t)(i * 8) * K_DIM + k0, &sA[(wave * 32 + i * 8) * BK]);
    #pragma unroll
    for (int i = 0; i < 2; i++)
      GLDS16(b_lane + (size_t)(i * 8) * K_DIM + k0, &sB[(wave * 16 + i * 8) * BK]);
    __syncthreads();

    #pragma unroll
    for (int kk = 0; kk < 2; kk++) {
      int slot = (kk * 4 + quad) ^ f7;
      bf16x8 bfr[2];
      #pragma unroll
      for (int ni = 0; ni < 2; ni++)
        bfr[ni] = *(const bf16x8*)&sB[(wn + ni * 16 + fm) * BK + slot * 8];
      #pragma unroll
      for (int mi = 0; mi < 8; mi++) {
        bf16x8 af = *(const bf16x8*)&sA[(wm + mi * 16 + fm) * BK + slot * 8];
        acc[mi][0] = __builtin_amdgcn_mfma_f32_16x16x32_bf16(af, bfr[0], acc[mi][0], 0, 0, 0);
        acc[mi][1] = __builtin_amdgcn_mfma_f32_16x16x32_bf16(af, bfr[1], acc[mi][1], 0, 0, 0);
      }
    }
    __syncthreads();
  }

  int slice = bn0 >> 10;
  int nd0   = bn0 & 1023;
  unsigned short* dst = (slice == 0) ? u_t : ((slice == 1) ? f_g : r_g);

  // four-chunk epilogue: rows [h*64, h*64+64) staged in 64*LDP shorts (17.4 KB)
  #pragma unroll
  for (int h = 0; h < 4; ++h) {
    if ((wave >> 2) == (h >> 1)) {
      #pragma unroll
      for (int ni = 0; ni < 2; ni++) {
        int lcol = wn + ni * 16 + fm;
        float bia = bias[bn0 + lcol];
        #pragma unroll
        for (int mq = 0; mq < 4; mq++) {
          int mi = (h & 1) * 4 + mq;
          #pragma unroll
          for (int reg = 0; reg < 4; reg++) {
            int lrow = mq * 16 + quad * 4 + reg;       // 0..63 within chunk
            float v = acc[mi][ni][reg] + bia;
            float act = (slice == 0) ? ftanh(v) : fsigmoid(v);
            smem[lrow * LDP + lcol] = f2bf(act);
          }
        }
      }
    }
    __syncthreads();
    #pragma unroll
    for (int it = 0; it < 2; ++it) {
      int row = it * 32 + (tid >> 4);                  // 0..63
      int cc  = (tid & 15) * 8;                        // 0..120
      u16x8 v = *(const u16x8*)&smem[row * LDP + cc];
      *(u16x8*)(dst + (size_t)(bm0 + h * 64 + row) * DD + nd0 + cc) = v;
    }
    __syncthreads();
  }
}

// ---- scan pass 1: per-segment affine summary, vec8 channels, 16B loads ----
// segment = 16 l-steps; P,E stored bf16 [NSEG][CH]
__global__ __launch_bounds__(256) void scan_pass1(const unsigned short* __restrict__ f_g,
                                                  const unsigned short* __restrict__ u_t,
                                                  unsigned short* __restrict__ P,
                                                  unsigned short* __restrict__ E)
{
  int vc8 = blockIdx.x * 256 + threadIdx.x;   // 0..1023
  int seg = blockIdx.y;                       // 0..127
  const u16x8* f8 = (const u16x8*)f_g;
  const u16x8* u8 = (const u16x8*)u_t;
  size_t g = (size_t)(seg * LSEG) * CH8 + vc8;
  float p[8], e[8];
  #pragma unroll
  for (int k = 0; k < 8; k++) { p[k] = 1.f; e[k] = 0.f; }
  #pragma unroll 4
  for (int i = 0; i < LSEG; i++) {
    u16x8 ff = f8[g];
    u16x8 uu = u8[g];
    #pragma unroll
    for (int k = 0; k < 8; k++) {
      float fv = bf2f(ff[k]);
      e[k] = fv * e[k] + (1.f - fv) * bf2f(uu[k]);
      p[k] *= fv;
    }
    g += CH8;
  }
  u16x8 pv, ev;
  #pragma unroll
  for (int k = 0; k < 8; k++) { pv[k] = f2bf(p[k]); ev[k] = f2bf(e[k]); }
  ((u16x8*)P)[(size_t)seg * CH8 + vc8] = pv;
  ((u16x8*)E)[(size_t)seg * CH8 + vc8] = ev;
}

// ---- scan pass 2: scan 128 segment summaries per channel ----
__global__ __launch_bounds__(128) void scan_pass2(const unsigned short* __restrict__ P,
                                                  const unsigned short* __restrict__ E,
                                                  const float* __restrict__ c0,
                                                  float* __restrict__ Cini,
                                                  float* __restrict__ lastc)
{
  int ch = blockIdx.x * 128 + threadIdx.x;    // 64 blocks x 128
  float c = c0[ch];
  #pragma unroll 8
  for (int s = 0; s < NSEG; s++) {
    Cini[(size_t)s * CH + ch] = c;
    c = bf2f(P[(size_t)s * CH + ch]) * c + bf2f(E[(size_t)s * CH + ch]);
  }
  lastc[ch] = c;
}

// ---- scan pass 3: replay with true init + fused output, vec8, 16B loads ----
__global__ __launch_bounds__(256) void scan_pass3(const unsigned short* __restrict__ f_g,
                                                  const unsigned short* __restrict__ u_t,
                                                  const unsigned short* __restrict__ r_g,
                                                  const float* __restrict__ x,
                                                  const unsigned short* __restrict__ xn,
                                                  const float* __restrict__ Cini,
                                                  float* __restrict__ out)
{
  int vc8 = blockIdx.x * 256 + threadIdx.x;   // 0..1023
  int seg = blockIdx.y;                       // 0..127
  const u16x8* f8 = (const u16x8*)f_g;
  const u16x8* u8 = (const u16x8*)u_t;
  const u16x8* r8 = (const u16x8*)r_g;
  const u16x8* n8 = (const u16x8*)xn;
  const float4* x4 = (const float4*)x;
  float4* o4 = (float4*)out;
  float c[8];
  {
    const float4* C4 = (const float4*)Cini;
    size_t ci = (size_t)seg * (CH / 4) + (size_t)vc8 * 2;
    float4 ca = C4[ci], cb = C4[ci + 1];
    c[0]=ca.x; c[1]=ca.y; c[2]=ca.z; c[3]=ca.w;
    c[4]=cb.x; c[5]=cb.y; c[6]=cb.z; c[7]=cb.w;
  }
  size_t g = (size_t)(seg * LSEG) * CH8 + vc8;
  #pragma unroll 2
  for (int i = 0; i < LSEG; i++) {
    u16x8 ff = f8[g];
    u16x8 uu = u8[g];
    u16x8 rr = r8[g];
    u16x8 nn = n8[g];
    size_t xi = g * 2;                 // float4 index (8 floats = 2 float4)
    float4 xa = x4[xi], xb = x4[xi + 1];
    float ov[8];
    #pragma unroll
    for (int k = 0; k < 8; k++) {
      float fv = bf2f(ff[k]);
      c[k] = fv * c[k] + (1.f - fv) * bf2f(uu[k]);
      float rv = bf2f(rr[k]);
      ov[k] = rv * ftanh(c[k]) + (1.f - rv) * bf2f(nn[k]);
    }
    o4[xi]     = (float4){xa.x + ov[0], xa.y + ov[1], xa.z + ov[2], xa.w + ov[3]};
    o4[xi + 1] = (float4){xb.x + ov[4], xb.y + ov[5], xb.z + ov[6], xb.w + ov[7]};
    g += CH8;
  }
}

extern "C" void kernel_launch(void* const* d_in, const int* in_sizes, int n_in,
                              void* d_out, int out_size, void* d_ws, size_t ws_size,
                              hipStream_t stream) {
  const float* x    = (const float*)d_in[0];
  const float* c0   = (const float*)d_in[1];
  const float* W    = (const float*)d_in[2];
  const float* bias = (const float*)d_in[3];
  const float* ln_g = (const float*)d_in[4];
  const float* ln_b = (const float*)d_in[5];
  float* out = (float*)d_out;

  char* ws = (char*)d_ws;
  unsigned short* xn  = (unsigned short*)(ws);                 // 33,554,432 B
  unsigned short* wb  = (unsigned short*)(ws + 33554432ULL);   //  6,291,456 B (dead after gemm)
  unsigned short* u_t = (unsigned short*)(ws + 39845888ULL);   // 33,554,432 B
  unsigned short* f_g = (unsigned short*)(ws + 73400320ULL);   // 33,554,432 B
  unsigned short* r_g = (unsigned short*)(ws + 106954752ULL);  // 33,554,432 B
  // P,E (bf16, 2 MB each) reuse wb's region after gemm completes:
  unsigned short* Pseg = (unsigned short*)(ws + 33554432ULL);  // 2,097,152 B
  unsigned short* Eseg = (unsigned short*)(ws + 35651584ULL);  // 2,097,152 B
  float* Cini = (float*)(ws + 140509184ULL);                   // 4,194,304 B (ends 144,703,488)

  ln_kernel   <<<M_DIM / 4, 256, 0, stream>>>(x, ln_g, ln_b, xn);
  wconv_kernel<<<N_DIM, 256, 0, stream>>>(W, wb);
  gemm_gates  <<<dim3(M_DIM / BM, N_DIM / BN), 512, 0, stream>>>(xn, wb, bias, u_t, f_g, r_g);
  scan_pass1  <<<dim3(CH8 / 256, NSEG), 256, 0, stream>>>(f_g, u_t, Pseg, Eseg);
  scan_pass2  <<<CH / 128, 128, 0, stream>>>(Pseg, Eseg, c0, Cini, out + (size_t)M_DIM * DD);
  scan_pass3  <<<dim3(CH8 / 256, NSEG), 256, 0, stream>>>(f_g, u_t, r_g, x, xn, Cini, out);
}

// Round 6
// 211.362 us; speedup vs baseline: 1.4979x; 1.1338x over previous
//
#include <hip/hip_runtime.h>

#define L_DIM 2048
#define B_DIM 8
#define DD    1024
#define M_DIM 16384     // L*B
#define N_DIM 3072      // 3*D
#define K_DIM 1024
#define CH    8192      // B*D channels
#define CH8   1024      // CH/8 (vec8 units per l-step)
#define NSEG  128
#define LSEG  16
#define LN_EPS 1e-5f

typedef __attribute__((ext_vector_type(8))) short bf16x8;
typedef __attribute__((ext_vector_type(8))) unsigned short u16x8;
typedef __attribute__((ext_vector_type(4))) float f32x4;

__device__ __forceinline__ unsigned short f2bf(float f){
  unsigned u = __float_as_uint(f);
  u += 0x7fffu + ((u >> 16) & 1u);
  return (unsigned short)(u >> 16);
}
__device__ __forceinline__ float bf2f(unsigned short h){
  return __uint_as_float(((unsigned)h) << 16);
}
__device__ __forceinline__ float fsigmoid(float z){ return 1.0f/(1.0f + __expf(-z)); }
__device__ __forceinline__ float ftanh(float z){ return 1.0f - 2.0f/(1.0f + __expf(2.0f*z)); }

// ------- LayerNorm: wave-per-row, 4 rows/block, no barriers -------
__global__ __launch_bounds__(256) void ln_kernel(const float* __restrict__ x,
                                                 const float* __restrict__ g,
                                                 const float* __restrict__ bta,
                                                 unsigned short* __restrict__ xn)
{
  int tid  = threadIdx.x;
  int wave = tid >> 6, lane = tid & 63;
  int row  = blockIdx.x * 4 + wave;
  const float4* xr = (const float4*)(x + (size_t)row * DD);
  float4 v[4];
  #pragma unroll
  for (int k = 0; k < 4; k++) v[k] = xr[lane + k * 64];
  float s = 0.f, sq = 0.f;
  #pragma unroll
  for (int k = 0; k < 4; k++) {
    s  += v[k].x + v[k].y + v[k].z + v[k].w;
    sq += v[k].x*v[k].x + v[k].y*v[k].y + v[k].z*v[k].z + v[k].w*v[k].w;
  }
  #pragma unroll
  for (int off = 32; off > 0; off >>= 1) {
    s  += __shfl_down(s,  off, 64);
    sq += __shfl_down(sq, off, 64);
  }
  s  = __shfl(s,  0, 64);
  sq = __shfl(sq, 0, 64);
  float mean = s * (1.0f / DD);
  float var  = sq * (1.0f / DD) - mean * mean;
  float rstd = rsqrtf(var + LN_EPS);
  ushort4* xo = (ushort4*)(xn + (size_t)row * DD);
  #pragma unroll
  for (int k = 0; k < 4; k++) {
    float4 gg = ((const float4*)g)[lane + k * 64];
    float4 bb = ((const float4*)bta)[lane + k * 64];
    ushort4 o;
    o.x = f2bf((v[k].x - mean) * rstd * gg.x + bb.x);
    o.y = f2bf((v[k].y - mean) * rstd * gg.y + bb.y);
    o.z = f2bf((v[k].z - mean) * rstd * gg.z + bb.z);
    o.w = f2bf((v[k].w - mean) * rstd * gg.w + bb.w);
    xo[lane + k * 64] = o;
  }
}

// ---------------- W fp32 [3072,1024] -> bf16 same layout ----------------
__global__ __launch_bounds__(256) void wconv_kernel(const float* __restrict__ W,
                                                    unsigned short* __restrict__ wb)
{
  int gid = blockIdx.x * 256 + threadIdx.x;
  float4 v = ((const float4*)W)[gid];
  ushort4 o;
  o.x = f2bf(v.x); o.y = f2bf(v.y); o.z = f2bf(v.z); o.w = f2bf(v.w);
  ((ushort4*)wb)[gid] = o;
}

// ---------------- GEMM: ufr = xn * W^T + b, fused activations ----------------
// BM=256 x BN=128, BK=64, 8 waves (2M x 4N; per-wave 128x32 -> acc[8][2] = 64
// AGPRs + 64 arch VGPRs = 128/wave -> 16 waves/CU, 2 blocks/CU co-resident).
// DEFAULT dispatch order (R5's XCD swizzle de-synchronized by-phases across
// XCDs -> each XCD streamed all of A per column phase -> FETCH 397 MB; default
// bx-fast order keeps the chip-wide resident window on one by-phase, sharing
// the A panel: R1-R3 measured 75 MB with this order).
#define BM 256
#define BN 128
#define BK 64
#define LDP 136        // epilogue chunk leading dim (shorts); 64*136*2 = 17.4 KB

#define GLDS16(gp, lp) __builtin_amdgcn_global_load_lds( \
    (const __attribute__((address_space(1))) void*)(gp), \
    (__attribute__((address_space(3))) void*)(lp), 16, 0, 0)

__global__ __launch_bounds__(512, 4) void gemm_gates(const unsigned short* __restrict__ A,
                                                     const unsigned short* __restrict__ Bw,
                                                     const float* __restrict__ bias,
                                                     unsigned short* __restrict__ u_t,
                                                     unsigned short* __restrict__ f_g,
                                                     unsigned short* __restrict__ r_g)
{
  __shared__ unsigned short smem[24576];          // 49,152 B
  unsigned short* sA = smem;                      // 256*64 shorts = 32 KB
  unsigned short* sB = smem + BM * BK;            // 128*64 shorts = 16 KB
  int tid  = threadIdx.x;
  int wave = tid >> 6, lane = tid & 63;

  int bm0 = blockIdx.x * BM;
  int bn0 = blockIdx.y * BN;

  f32x4 zero = {0.f, 0.f, 0.f, 0.f};
  f32x4 acc[8][2];
  #pragma unroll
  for (int i = 0; i < 8; i++)
    #pragma unroll
    for (int j = 0; j < 2; j++) acc[i][j] = zero;

  int q8  = lane >> 3;
  int rr8 = lane & 7;
  int sch = rr8 ^ q8;        // XOR swizzle source chunk
  const unsigned short* a_lane = A  + (size_t)(bm0 + wave * 32 + q8) * K_DIM + sch * 8;
  const unsigned short* b_lane = Bw + (size_t)(bn0 + wave * 16 + q8) * K_DIM + sch * 8;

  int wm = (wave >> 2) * 128, wn = (wave & 3) * 32;   // per-wave output origin
  int fm = lane & 15, quad = lane >> 4;
  int f7 = fm & 7;

  for (int k0 = 0; k0 < K_DIM; k0 += BK) {
    #pragma unroll
    for (int i = 0; i < 4; i++)
      GLDS16(a_lane + (size_t)(i * 8) * K_DIM + k0, &sA[(wave * 32 + i * 8) * BK]);
    #pragma unroll
    for (int i = 0; i < 2; i++)
      GLDS16(b_lane + (size_t)(i * 8) * K_DIM + k0, &sB[(wave * 16 + i * 8) * BK]);
    __syncthreads();

    #pragma unroll
    for (int kk = 0; kk < 2; kk++) {
      int slot = (kk * 4 + quad) ^ f7;
      bf16x8 bfr[2];
      #pragma unroll
      for (int ni = 0; ni < 2; ni++)
        bfr[ni] = *(const bf16x8*)&sB[(wn + ni * 16 + fm) * BK + slot * 8];
      #pragma unroll
      for (int mi = 0; mi < 8; mi++) {
        bf16x8 af = *(const bf16x8*)&sA[(wm + mi * 16 + fm) * BK + slot * 8];
        acc[mi][0] = __builtin_amdgcn_mfma_f32_16x16x32_bf16(af, bfr[0], acc[mi][0], 0, 0, 0);
        acc[mi][1] = __builtin_amdgcn_mfma_f32_16x16x32_bf16(af, bfr[1], acc[mi][1], 0, 0, 0);
      }
    }
    __syncthreads();
  }

  int slice = bn0 >> 10;
  int nd0   = bn0 & 1023;
  unsigned short* dst = (slice == 0) ? u_t : ((slice == 1) ? f_g : r_g);

  // four-chunk epilogue: rows [h*64, h*64+64) staged in 64*LDP shorts (17.4 KB)
  #pragma unroll
  for (int h = 0; h < 4; ++h) {
    if ((wave >> 2) == (h >> 1)) {
      #pragma unroll
      for (int ni = 0; ni < 2; ni++) {
        int lcol = wn + ni * 16 + fm;
        float bia = bias[bn0 + lcol];
        #pragma unroll
        for (int mq = 0; mq < 4; mq++) {
          int mi = (h & 1) * 4 + mq;
          #pragma unroll
          for (int reg = 0; reg < 4; reg++) {
            int lrow = mq * 16 + quad * 4 + reg;       // 0..63 within chunk
            float v = acc[mi][ni][reg] + bia;
            float act = (slice == 0) ? ftanh(v) : fsigmoid(v);
            smem[lrow * LDP + lcol] = f2bf(act);
          }
        }
      }
    }
    __syncthreads();
    #pragma unroll
    for (int it = 0; it < 2; ++it) {
      int row = it * 32 + (tid >> 4);                  // 0..63
      int cc  = (tid & 15) * 8;                        // 0..120
      u16x8 v = *(const u16x8*)&smem[row * LDP + cc];
      *(u16x8*)(dst + (size_t)(bm0 + h * 64 + row) * DD + nd0 + cc) = v;
    }
    __syncthreads();
  }
}

// ---- scan pass 1: per-segment affine summary, vec8 channels, 16B loads ----
// segment = 16 l-steps; P,E stored bf16 [NSEG][CH]
__global__ __launch_bounds__(256) void scan_pass1(const unsigned short* __restrict__ f_g,
                                                  const unsigned short* __restrict__ u_t,
                                                  unsigned short* __restrict__ P,
                                                  unsigned short* __restrict__ E)
{
  int vc8 = blockIdx.x * 256 + threadIdx.x;   // 0..1023
  int seg = blockIdx.y;                       // 0..127
  const u16x8* f8 = (const u16x8*)f_g;
  const u16x8* u8 = (const u16x8*)u_t;
  size_t g = (size_t)(seg * LSEG) * CH8 + vc8;
  float p[8], e[8];
  #pragma unroll
  for (int k = 0; k < 8; k++) { p[k] = 1.f; e[k] = 0.f; }
  #pragma unroll 4
  for (int i = 0; i < LSEG; i++) {
    u16x8 ff = f8[g];
    u16x8 uu = u8[g];
    #pragma unroll
    for (int k = 0; k < 8; k++) {
      float fv = bf2f(ff[k]);
      e[k] = fv * e[k] + (1.f - fv) * bf2f(uu[k]);
      p[k] *= fv;
    }
    g += CH8;
  }
  u16x8 pv, ev;
  #pragma unroll
  for (int k = 0; k < 8; k++) { pv[k] = f2bf(p[k]); ev[k] = f2bf(e[k]); }
  ((u16x8*)P)[(size_t)seg * CH8 + vc8] = pv;
  ((u16x8*)E)[(size_t)seg * CH8 + vc8] = ev;
}

// ---- scan pass 2: scan 128 segment summaries per channel ----
__global__ __launch_bounds__(128) void scan_pass2(const unsigned short* __restrict__ P,
                                                  const unsigned short* __restrict__ E,
                                                  const float* __restrict__ c0,
                                                  float* __restrict__ Cini,
                                                  float* __restrict__ lastc)
{
  int ch = blockIdx.x * 128 + threadIdx.x;    // 64 blocks x 128
  float c = c0[ch];
  #pragma unroll 8
  for (int s = 0; s < NSEG; s++) {
    Cini[(size_t)s * CH + ch] = c;
    c = bf2f(P[(size_t)s * CH + ch]) * c + bf2f(E[(size_t)s * CH + ch]);
  }
  lastc[ch] = c;
}

// ---- scan pass 3: replay with true init + fused output, vec8, 16B loads ----
__global__ __launch_bounds__(256) void scan_pass3(const unsigned short* __restrict__ f_g,
                                                  const unsigned short* __restrict__ u_t,
                                                  const unsigned short* __restrict__ r_g,
                                                  const float* __restrict__ x,
                                                  const unsigned short* __restrict__ xn,
                                                  const float* __restrict__ Cini,
                                                  float* __restrict__ out)
{
  int vc8 = blockIdx.x * 256 + threadIdx.x;   // 0..1023
  int seg = blockIdx.y;                       // 0..127
  const u16x8* f8 = (const u16x8*)f_g;
  const u16x8* u8 = (const u16x8*)u_t;
  const u16x8* r8 = (const u16x8*)r_g;
  const u16x8* n8 = (const u16x8*)xn;
  const float4* x4 = (const float4*)x;
  float4* o4 = (float4*)out;
  float c[8];
  {
    const float4* C4 = (const float4*)Cini;
    size_t ci = (size_t)seg * (CH / 4) + (size_t)vc8 * 2;
    float4 ca = C4[ci], cb = C4[ci + 1];
    c[0]=ca.x; c[1]=ca.y; c[2]=ca.z; c[3]=ca.w;
    c[4]=cb.x; c[5]=cb.y; c[6]=cb.z; c[7]=cb.w;
  }
  size_t g = (size_t)(seg * LSEG) * CH8 + vc8;
  #pragma unroll 2
  for (int i = 0; i < LSEG; i++) {
    u16x8 ff = f8[g];
    u16x8 uu = u8[g];
    u16x8 rr = r8[g];
    u16x8 nn = n8[g];
    size_t xi = g * 2;                 // float4 index (8 floats = 2 float4)
    float4 xa = x4[xi], xb = x4[xi + 1];
    float ov[8];
    #pragma unroll
    for (int k = 0; k < 8; k++) {
      float fv = bf2f(ff[k]);
      c[k] = fv * c[k] + (1.f - fv) * bf2f(uu[k]);
      float rv = bf2f(rr[k]);
      ov[k] = rv * ftanh(c[k]) + (1.f - rv) * bf2f(nn[k]);
    }
    o4[xi]     = (float4){xa.x + ov[0], xa.y + ov[1], xa.z + ov[2], xa.w + ov[3]};
    o4[xi + 1] = (float4){xb.x + ov[4], xb.y + ov[5], xb.z + ov[6], xb.w + ov[7]};
    g += CH8;
  }
}

extern "C" void kernel_launch(void* const* d_in, const int* in_sizes, int n_in,
                              void* d_out, int out_size, void* d_ws, size_t ws_size,
                              hipStream_t stream) {
  const float* x    = (const float*)d_in[0];
  const float* c0   = (const float*)d_in[1];
  const float* W    = (const float*)d_in[2];
  const float* bias = (const float*)d_in[3];
  const float* ln_g = (const float*)d_in[4];
  const float* ln_b = (const float*)d_in[5];
  float* out = (float*)d_out;

  char* ws = (char*)d_ws;
  unsigned short* xn  = (unsigned short*)(ws);                 // 33,554,432 B
  unsigned short* wb  = (unsigned short*)(ws + 33554432ULL);   //  6,291,456 B (dead after gemm)
  unsigned short* u_t = (unsigned short*)(ws + 39845888ULL);   // 33,554,432 B
  unsigned short* f_g = (unsigned short*)(ws + 73400320ULL);   // 33,554,432 B
  unsigned short* r_g = (unsigned short*)(ws + 106954752ULL);  // 33,554,432 B
  // P,E (bf16, 2 MB each) reuse wb's region after gemm completes:
  unsigned short* Pseg = (unsigned short*)(ws + 33554432ULL);  // 2,097,152 B
  unsigned short* Eseg = (unsigned short*)(ws + 35651584ULL);  // 2,097,152 B
  float* Cini = (float*)(ws + 140509184ULL);                   // 4,194,304 B (ends 144,703,488)

  ln_kernel   <<<M_DIM / 4, 256, 0, stream>>>(x, ln_g, ln_b, xn);
  wconv_kernel<<<N_DIM, 256, 0, stream>>>(W, wb);
  gemm_gates  <<<dim3(M_DIM / BM, N_DIM / BN), 512, 0, stream>>>(xn, wb, bias, u_t, f_g, r_g);
  scan_pass1  <<<dim3(CH8 / 256, NSEG), 256, 0, stream>>>(f_g, u_t, Pseg, Eseg);
  scan_pass2  <<<CH / 128, 128, 0, stream>>>(Pseg, Eseg, c0, Cini, out + (size_t)M_DIM * DD);
  scan_pass3  <<<dim3(CH8 / 256, NSEG), 256, 0, stream>>>(f_g, u_t, r_g, x, xn, Cini, out);
}